// Round 12
// baseline (137.221 us; speedup 1.0000x reference)
//
#include <hip/hip_runtime.h>
#include <stdint.h>

#define IN_F 4096
#define OUT_F 4096
#define NG 32
#define NSTEP 32   // (K/2)/64 k-steps per half (in-block split-K)

typedef __attribute__((ext_vector_type(8))) _Float16 half8;
typedef __attribute__((ext_vector_type(2))) _Float16 half2t;
typedef __attribute__((ext_vector_type(4))) float floatx4;

__device__ __forceinline__ unsigned pkh(float a, float b) {
  return __builtin_bit_cast(unsigned, __builtin_amdgcn_cvt_pkrtz(a, b));
}

// ---------------------------------------------------------------------------
// Prep (R4-verified): x f32 -> fp16 pair-permuted; scale/zero -> fp16x2 table.
// ---------------------------------------------------------------------------
__global__ __launch_bounds__(256) void prep_kernel(
    const float* __restrict__ x, _Float16* __restrict__ Xh,
    const float* __restrict__ wscale, const int* __restrict__ wzero,
    uint2* __restrict__ SZ, int nxb) {
  int b = blockIdx.x;
  if (b < nxb) {
    int i = b * 256 + threadIdx.x;
    const float4* x4 = (const float4*)x;
    float4 a = x4[2 * i];
    float4 c = x4[2 * i + 1];
    uint4 o;
    o.x = pkh(a.x, c.x);   // (x0,x4)
    o.y = pkh(a.y, c.y);
    o.z = pkh(a.z, c.z);
    o.w = pkh(a.w, c.w);
    ((uint4*)Xh)[i] = o;
  } else {
    int i = (b - nxb) * 256 + threadIdx.x;
    float s = wscale[i];
    int zp = wzero[i];
    _Float16 sh = (_Float16)s;
    _Float16 ch = (_Float16)(float)(1032 + zp);  // exact in fp16
    unsigned s2 = (unsigned)__builtin_bit_cast(unsigned short, sh) * 0x10001u;
    unsigned c2 = (unsigned)__builtin_bit_cast(unsigned short, ch) * 0x10001u;
    SZ[i] = make_uint2(s2, c2);
  }
}

// Magic-number nibble dequant: one packed int32 -> one b128 MFMA B-fragment
// (8 fp16, pair-permuted to match prep's A pairing).
__device__ __forceinline__ half8 dequant8(unsigned v, uint2 szv) {
  unsigned tx = v ^ 0x88888888u;
  half2t s2 = __builtin_bit_cast(half2t, szv.x);
  half2t c2 = __builtin_bit_cast(half2t, szv.y);
  unsigned p0 = (tx & 0x000F000Fu) | 0x64006400u;          // (n0, n4)
  unsigned p1 = ((tx >> 4) & 0x000F000Fu) | 0x64006400u;   // (n1, n5)
  unsigned p2 = ((tx >> 8) & 0x000F000Fu) | 0x64006400u;   // (n2, n6)
  unsigned p3 = ((tx >> 12) & 0x000F000Fu) | 0x64006400u;  // (n3, n7)
  half2t w0 = (__builtin_bit_cast(half2t, p0) - c2) * s2;
  half2t w1 = (__builtin_bit_cast(half2t, p1) - c2) * s2;
  half2t w2 = (__builtin_bit_cast(half2t, p2) - c2) * s2;
  half2t w3 = (__builtin_bit_cast(half2t, p3) - c2) * s2;
  uint4 o;
  o.x = __builtin_bit_cast(unsigned, w0);
  o.y = __builtin_bit_cast(unsigned, w1);
  o.z = __builtin_bit_cast(unsigned, w2);
  o.w = __builtin_bit_cast(unsigned, w3);
  return __builtin_bit_cast(half8, o);
}

// ---------------------------------------------------------------------------
// Fused W4A16 GEMM = R4 skeleton with PACKED-B LDS (consumer-side dequant).
// LDS is the serialized CU resource (per-step cycle model: R4 ~2200 cy ->
// this ~1590 cy). B stored as int32 (4 ds_write_b32/thread, 8 KB/step);
// consumer does ds_read_b32 + dequant8 into the MFMA B-operand.
// Bank math: writes <=2-way, reads <=2-way via slot = chunk ^ (row&7)
// involution (2-way is free, m136). A path, barriers, split-K epilogue,
// XOR A-swizzle: R4 verbatim. LDS 80 KB.
// Scales consumer-side: szA/szB named uint2[4] sets, 4-step unrolled loop,
// loaded once per 2 steps under the MFMA phase (L2-hot SZ table).
// ---------------------------------------------------------------------------
__global__ __launch_bounds__(512, 2) void gemm_fused(
    const _Float16* __restrict__ A, const int* __restrict__ wp,
    const uint2* __restrict__ SZ, float* __restrict__ out,
    int M, int N, int K) {
  __shared__ __align__(16) _Float16 Alds[4 * 8192];  // [half*2+buf][128x64] 64 KB
  __shared__ unsigned Bpk[2 * 2 * 1024];             // [buf*2+half][row*8+slot] 16 KB

  const int t = threadIdx.x;
  const int wave = t >> 6, lane = t & 63;
  const int h = wave >> 2, w2 = wave & 3;
  const int wm = (w2 >> 1) * 64, wn = (w2 & 1) * 64;
  const int r = lane & 15, quad = lane >> 4, rb = r & 7;
  const int bm = blockIdx.y * 128, bn = blockIdx.x * 128;

  floatx4 acc[4][4] = {};

  // ---- A staging (R4): LDS (row,kc) holds global chunk kc^(row&7); swizzle
  // on the GLOBAL source address, LDS dest lane-linear. ----
  const int kc = t & 7, row0 = t >> 3, row1 = row0 + 64;
  const int gkc = kc ^ (row0 & 7);
  const _Float16* Ag = A + (size_t)bm * K;
  const _Float16* gA[4];
  gA[0] = Ag + (size_t)row0 * K + gkc * 8;          // half 0
  gA[1] = Ag + (size_t)row1 * K + gkc * 8;
  gA[2] = gA[0] + 2048;                             // half 1
  gA[3] = gA[1] + 2048;

#define STAGE_A(i, buf)                                                       \
  {                                                                           \
    _Pragma("unroll") for (int j = 0; j < 4; ++j) {                           \
      const _Float16* src = gA[j] + (i) * 64;                                 \
      int dst = ((j >> 1) * 2 + (buf)) * 8192 + (t + 512 * (j & 1)) * 8;      \
      __builtin_amdgcn_global_load_lds(                                       \
          (const __attribute__((address_space(1))) void*)src,                 \
          (__attribute__((address_space(3))) void*)(&Alds[dst]), 16, 0, 0);   \
    }                                                                         \
  }

  // ---- B producer: coalesced int32 loads, packed ds_write_b32 (no dequant).
  const int brow0 = t >> 3, kc8 = t & 7;
  const int* gB0 = wp + (size_t)(bn + brow0) * (IN_F / 8) + kc8;
  const int* gB1 = wp + (size_t)(bn + brow0 + 64) * (IN_F / 8) + kc8;
  const int bsl = kc8 ^ (brow0 & 7);                // swizzled slot (involution)

#define LOADV_B(i, v)                                                         \
  {                                                                           \
    v[0] = (unsigned)gB0[(i) * 8];                                            \
    v[1] = (unsigned)gB1[(i) * 8];                                            \
    v[2] = (unsigned)gB0[(i) * 8 + 256];                                      \
    v[3] = (unsigned)gB1[(i) * 8 + 256];                                      \
  }

#define WRITE_BP(v, buf)                                                      \
  {                                                                           \
    unsigned* b0 = &Bpk[((buf) * 2 + 0) * 1024];                              \
    unsigned* b1 = &Bpk[((buf) * 2 + 1) * 1024];                              \
    b0[brow0 * 8 + bsl] = v[0];                                               \
    b0[(brow0 + 64) * 8 + bsl] = v[1];                                        \
    b1[brow0 * 8 + bsl] = v[2];                                               \
    b1[(brow0 + 64) * 8 + bsl] = v[3];                                        \
  }

  // ---- consumer-side scales: lane's 4 output rows, group = h*16 + pair ----
  const uint2* gSc[4];
#pragma unroll
  for (int ni = 0; ni < 4; ++ni)
    gSc[ni] = SZ + (size_t)(bn + wn + ni * 16 + r) * NG + h * 16;

#define LOADV_S(dst, p)                                                       \
  {                                                                           \
    _Pragma("unroll") for (int ni = 0; ni < 4; ++ni) dst[ni] = gSc[ni][(p)];  \
  }

#define COMPUTE(buf, szp)                                                     \
  {                                                                           \
    const _Float16* Ab = &Alds[(h * 2 + (buf)) * 8192];                       \
    const unsigned* Bb = &Bpk[((buf) * 2 + h) * 1024];                        \
    _Pragma("unroll") for (int ks = 0; ks < 2; ++ks) {                        \
      half8 af[4], bf[4];                                                     \
      _Pragma("unroll") for (int mi = 0; mi < 4; ++mi) {                      \
        int R = wm + mi * 16 + r;                                             \
        af[mi] = *(const half8*)&Alds[(h * 2 + (buf)) * 8192 + R * 64 +       \
                                      (((ks * 4 + quad) ^ rb) << 3)];         \
      }                                                                       \
      _Pragma("unroll") for (int ni = 0; ni < 4; ++ni) {                      \
        int R = wn + ni * 16 + r;                                             \
        unsigned bq = Bb[R * 8 + ((ks * 4 + quad) ^ rb)];                     \
        bf[ni] = dequant8(bq, szp[ni]);                                       \
      }                                                                       \
      _Pragma("unroll") for (int mi = 0; mi < 4; ++mi)                        \
        _Pragma("unroll") for (int ni = 0; ni < 4; ++ni)                      \
          acc[mi][ni] = __builtin_amdgcn_mfma_f32_16x16x32_f16(               \
              af[mi], bf[ni], acc[mi][ni], 0, 0, 0);                          \
    }                                                                         \
  }

  unsigned vA[4], vB[4];
  uint2 szA[4], szB[4];

  // ---- prologue ----
  LOADV_B(0, vA);
  LOADV_S(szA, 0);                    // pair 0
  STAGE_A(0, 0);
  WRITE_BP(vA, 0);
  LOADV_B(1, vB);
  __syncthreads();                    // drains A(0) DMA + B(0) writes

  // 4-step unrolled main loop: buf pattern 0,1,0,1; v sets alternate per
  // step; sz sets alternate per PAIR (loaded one step before first use).
  for (int i = 0; i < NSTEP; i += 4) {
    // step i: compute buf0 w/ szA (pair i/2); stage i+1 -> buf1
    if (i + 1 < NSTEP) { STAGE_A(i + 1, 1); WRITE_BP(vB, 1); }
    if (i + 2 < NSTEP) LOADV_B(i + 2, vA);
    COMPUTE(0, szA);
    __syncthreads();
    // step i+1: compute buf1 w/ szA; stage i+2 -> buf0; load szB (pair i/2+1)
    if (i + 2 < NSTEP) { STAGE_A(i + 2, 0); WRITE_BP(vA, 0); }
    if (i + 3 < NSTEP) LOADV_B(i + 3, vB);
    if (i + 2 < NSTEP) LOADV_S(szB, (i + 2) >> 1);
    COMPUTE(1, szA);
    __syncthreads();
    // step i+2: compute buf0 w/ szB; stage i+3 -> buf1
    if (i + 3 < NSTEP) { STAGE_A(i + 3, 1); WRITE_BP(vB, 1); }
    if (i + 4 < NSTEP) LOADV_B(i + 4, vA);
    COMPUTE(0, szB);
    __syncthreads();
    // step i+3: compute buf1 w/ szB; stage i+4 -> buf0; load szA (pair i/2+2)
    if (i + 4 < NSTEP) { STAGE_A(i + 4, 0); WRITE_BP(vA, 0); }
    if (i + 5 < NSTEP) LOADV_B(i + 5, vB);
    if (i + 4 < NSTEP) LOADV_S(szA, (i + 4) >> 1);
    COMPUTE(1, szB);
    __syncthreads();
  }

  // ---- in-block split-K reduction (reuse A LDS region) ----
  floatx4* red = (floatx4*)Alds;
  if (h == 1) {
#pragma unroll
    for (int mi = 0; mi < 4; ++mi)
#pragma unroll
      for (int ni = 0; ni < 4; ++ni)
        red[(mi * 4 + ni) * 256 + w2 * 64 + lane] = acc[mi][ni];
  }
  __syncthreads();
  if (h == 0) {
#pragma unroll
    for (int mi = 0; mi < 4; ++mi) {
#pragma unroll
      for (int ni = 0; ni < 4; ++ni) {
        acc[mi][ni] += red[(mi * 4 + ni) * 256 + w2 * 64 + lane];
#pragma unroll
        for (int i2 = 0; i2 < 4; ++i2) {
          int grow = bm + wm + mi * 16 + quad * 4 + i2;
          int gcol = bn + wn + ni * 16 + r;
          out[(size_t)grow * N + gcol] = acc[mi][ni][i2];
        }
      }
    }
  }
}

extern "C" void kernel_launch(void* const* d_in, const int* in_sizes, int n_in,
                              void* d_out, int out_size, void* d_ws, size_t ws_size,
                              hipStream_t stream) {
  const float* x = (const float*)d_in[0];
  const int* wp = (const int*)d_in[1];
  const float* wscale = (const float*)d_in[2];
  const int* wzero = (const int*)d_in[3];
  float* out = (float*)d_out;

  int M = in_sizes[0] / IN_F;  // 1024

  // Workspace: Xh (fp16 M*K = 8.39 MB) | SZ (1 MB)
  _Float16* Xh = (_Float16*)d_ws;
  uint2* SZ = (uint2*)((char*)d_ws + (size_t)M * IN_F * 2);

  int nxb = (M * IN_F / 8) / 256;       // 2048 blocks for x-convert
  int nzb = (OUT_F * NG) / 256;         // 512 blocks for scale/zero table
  prep_kernel<<<nxb + nzb, 256, 0, stream>>>(x, Xh, wscale, wzero, SZ, nxb);

  dim3 grid(OUT_F / 128, M / 128);      // (32, 8) = 256 blocks = 1/CU
  gemm_fused<<<grid, 512, 0, stream>>>(Xh, wp, SZ, out, M, OUT_F, IN_F);
}